// Round 19
// baseline (270.745 us; speedup 1.0000x reference)
//
#include <hip/hip_runtime.h>

#define NCH 128
#define NREL 64
#define NBP 1024      // max 128-dst buckets
#define ESB 4096      // edges per count/scatter block
#define CAPF 3072     // max edges per bucket (mean ~2048)
#define CAPH 2048     // max edges per 64-dst half-bucket (mean ~1024)
#define KTOT 1152     // 1024 z-K (kappa = ch*8 + b) + 128 root-K
#define KST 36        // KTOT/32 k-steps
#define ZROW 2304     // bytes per z row (1152 bf16)

typedef __attribute__((ext_vector_type(8))) short bf16x8;
typedef __attribute__((ext_vector_type(4))) float f32x4;

__device__ __forceinline__ unsigned short f2bf(float f) {
    unsigned u = __float_as_uint(f);
    return (unsigned short)((u + 0x7fffu + ((u >> 16) & 1u)) >> 16);  // RNE
}
__device__ __forceinline__ unsigned pack2bf(float a, float b) {
    return (unsigned)f2bf(a) | ((unsigned)f2bf(b) << 16);
}

// ---------------- x (fp32) -> x_sw (bf16, channel-swizzled: i = l15*8+nt <-> c = nt*16+l15)
__global__ __launch_bounds__(256) void k_prep(const float* __restrict__ x,
                                              unsigned short* __restrict__ xsw,
                                              int N) {
    int idx = blockIdx.x * 256 + threadIdx.x;
    if (idx >= N * 16) return;
    int n = idx >> 4, l15 = idx & 15;
    const float* xr = x + (size_t)n * NCH + l15;
    bf16x8 p;
#pragma unroll
    for (int nt = 0; nt < 8; ++nt) p[nt] = (short)f2bf(xr[nt * 16]);
    *(bf16x8*)(xsw + (size_t)n * NCH + l15 * 8) = p;
}

// -------- basisP (MFMA-A layout): k<1024 -> basis[k&7][k>>3][oc]; root rows permuted -------
// -------- attB[65][16] bf16: rows 0-63 = att (cols 8-15 zero), row 64 = zeros -------------
__global__ __launch_bounds__(256) void k_buildB(const float* __restrict__ basis,
                                                const float* __restrict__ att,
                                                const float* __restrict__ rw,
                                                unsigned short* __restrict__ attB,
                                                unsigned short* __restrict__ basisP) {
    int idx = blockIdx.x * 256 + threadIdx.x;
    if (idx < 1040) {
        int rr = idx >> 4, b = idx & 15;
        attB[idx] = (rr < NREL && b < 8) ? f2bf(att[rr * 8 + b]) : (unsigned short)0;
    }
    if (idx >= 128 * KTOT) return;
    int j = idx & 7, lg = (idx >> 3) & 3, oc = (idx >> 5) & 127, kk = idx >> 12;
    int k = kk * 32 + lg * 8 + j;
    float v;
    if (k < 1024) {
        int b = k & 7, ch = k >> 3;
        v = basis[(size_t)b * NCH * NCH + (size_t)ch * NCH + oc];
    } else {
        int kp = k - 1024;
        int ic = ((kp & 7) << 4) | (kp >> 3);  // x_sw channel permutation
        v = rw[(size_t)ic * NCH + oc];
    }
    basisP[idx] = f2bf(v);
}

// ---------------- per-block bucket histograms (no global atomics) ----------------
__global__ __launch_bounds__(256) void k_count(const int* __restrict__ trip, int E, int NB,
                                               int* __restrict__ cntB) {
    __shared__ int hb[NBP];
    int t = threadIdx.x;
    for (int i = t; i < NB; i += 256) hb[i] = 0;
    __syncthreads();
    int base = blockIdx.x * ESB;
#pragma unroll
    for (int i = 0; i < ESB / 256; ++i) {
        int e = base + i * 256 + t;
        if (e < E) atomicAdd(&hb[trip[3 * e + 2] >> 7], 1);
    }
    __syncthreads();
    for (int i = t; i < NB; i += 256) cntB[(size_t)blockIdx.x * NB + i] = hb[i];
}

// ---------------- column scan over blocks: cntB -> exclusive; bhist totals ----------------
__global__ __launch_bounds__(1024) void k_scanB(int* __restrict__ cntB, int GB, int NB,
                                                int* __restrict__ bhist) {
    __shared__ int sc[1024];
    int t = threadIdx.x, b = blockIdx.x;
    int v = (t < GB) ? cntB[(size_t)t * NB + b] : 0;
    sc[t] = v;
    __syncthreads();
    for (int off = 1; off < 1024; off <<= 1) {
        int a = (t >= off) ? sc[t - off] : 0;
        __syncthreads();
        sc[t] += a;
        __syncthreads();
    }
    if (t < GB) cntB[(size_t)t * NB + b] = sc[t] - v;
    if (t == GB - 1) bhist[b] = sc[t];
}

// ---------------- bucketoff from bhist ----------------
__global__ __launch_bounds__(1024) void k_offsets(const int* __restrict__ bhist, int NB,
                                                  int* __restrict__ bucketoff) {
    __shared__ int sc[1024];
    int t = threadIdx.x;
    int d = (t < NB) ? bhist[t] : 0;
    sc[t] = d;
    __syncthreads();
    for (int off = 1; off < 1024; off <<= 1) {
        int a = (t >= off) ? sc[t - off] : 0;
        __syncthreads();
        sc[t] += a;
        __syncthreads();
    }
    if (t < NB) bucketoff[t] = sc[t] - d;
    if (t == NB - 1) bucketoff[NB] = sc[t];
}

// ---------------- scatter: bucket-sorted packed edges (dst_low<<23 | rel<<17 | src) --------
__global__ __launch_bounds__(256) void k_scatter(const int* __restrict__ trip, int E, int NB,
                                                 const int* __restrict__ cntB,
                                                 const int* __restrict__ bucketoff,
                                                 unsigned* __restrict__ packed) {
    __shared__ int cb[NBP], lbase[NBP], delta[NBP];
    __shared__ int ssc[256];
    __shared__ unsigned lpk[ESB];
    __shared__ unsigned short lb[ESB];
    int t = threadIdx.x, blk = blockIdx.x;
    for (int i = t; i < NB; i += 256) cb[i] = 0;
    __syncthreads();
    int base = blk * ESB;
    int total = min(ESB, E - base);

    unsigned pk[ESB / 256];
    int rk[ESB / 256];
    unsigned short bk[ESB / 256];
#pragma unroll
    for (int i = 0; i < ESB / 256; ++i) {
        int e = base + i * 256 + t;
        pk[i] = 0; rk[i] = 0; bk[i] = 0;
        if (e < E) {
            int src = trip[3 * e], rel = trip[3 * e + 1], dst = trip[3 * e + 2];
            int bkt = dst >> 7;
            bk[i] = (unsigned short)bkt;
            pk[i] = ((unsigned)(dst & 127) << 23) | ((unsigned)rel << 17) | (unsigned)src;
            rk[i] = atomicAdd(&cb[bkt], 1);
        }
    }
    __syncthreads();
    int ch = (NB + 255) >> 8;
    int mysum = 0;
    for (int i = 0; i < ch; ++i) {
        int idx = t * ch + i;
        if (idx < NB) mysum += cb[idx];
    }
    ssc[t] = mysum;
    __syncthreads();
    for (int off = 1; off < 256; off <<= 1) {
        int a = (t >= off) ? ssc[t - off] : 0;
        __syncthreads();
        ssc[t] += a;
        __syncthreads();
    }
    int run = ssc[t] - mysum;
    for (int i = 0; i < ch; ++i) {
        int idx = t * ch + i;
        if (idx < NB) { lbase[idx] = run; run += cb[idx]; }
    }
    __syncthreads();
    for (int i = t; i < NB; i += 256)
        delta[i] = bucketoff[i] + cntB[(size_t)blk * NB + i] - lbase[i];
    __syncthreads();
#pragma unroll
    for (int i = 0; i < ESB / 256; ++i) {
        int e = base + i * 256 + t;
        if (e < E) {
            int j = lbase[bk[i]] + rk[i];
            lpk[j] = pk[i];
            lb[j] = bk[i];
        }
    }
    __syncthreads();
    for (int j = t; j < total; j += 256)
        packed[delta[lb[j]] + j] = lpk[j];
}

// ---------------- per-bucket dst_low counting sort -> sortedG + dstoffG ----------------
__global__ __launch_bounds__(256) void k_sortbkt(const unsigned* __restrict__ packed,
                                                 const int* __restrict__ bucketoff,
                                                 unsigned* __restrict__ sortedG,
                                                 int* __restrict__ dstoffG) {
    __shared__ int h[128], hs[128];
    int t = threadIdx.x, b = blockIdx.x;
    if (t < 128) h[t] = 0;
    __syncthreads();
    int s0 = bucketoff[b], s1 = bucketoff[b + 1];
    int cnt = min(s1 - s0, CAPF);

    unsigned pk[CAPF / 256];
    int rk[CAPF / 256];
#pragma unroll
    for (int i = 0; i < CAPF / 256; ++i) {
        int j = i * 256 + t;
        pk[i] = 0; rk[i] = 0;
        if (j < cnt) {
            unsigned p = packed[s0 + j];
            pk[i] = p;
            rk[i] = atomicAdd(&h[p >> 23], 1);
        }
    }
    __syncthreads();
    if (t < 128) hs[t] = h[t];
    __syncthreads();
    for (int off = 1; off < 128; off <<= 1) {
        int a = (t < 128 && t >= off) ? hs[t - off] : 0;
        __syncthreads();
        if (t < 128) hs[t] += a;
        __syncthreads();
    }
    if (t < 128) dstoffG[b * 129 + t] = hs[t] - h[t];  // exclusive, bucket-relative
    if (t == 0) dstoffG[b * 129 + 128] = cnt;
#pragma unroll
    for (int i = 0; i < CAPF / 256; ++i) {
        int j = i * 256 + t;
        if (j < cnt) {
            int d = pk[i] >> 23;
            sortedG[s0 + hs[d] - h[d] + rk[i]] = pk[i];
        }
    }
}

// ------------- fused: per-dst mini-MFMA, nt split at DST level (acc[4] live) + big MFMA ----
__global__ __launch_bounds__(512, 4) void k_fused(const unsigned* __restrict__ x32,
                                                  const char* __restrict__ xswb,
                                                  const unsigned* __restrict__ sortedG,
                                                  const int* __restrict__ bucketoff,
                                                  const int* __restrict__ dstoffG,
                                                  const unsigned short* __restrict__ attBg,
                                                  const unsigned short* __restrict__ basisP,
                                                  const float* __restrict__ rb,
                                                  float* __restrict__ out, int N) {
    __shared__ bf16x8 ztV[16 * (ZROW / 16)];   // 36 KB swizzled Z' tile (16 dsts x 1152 bf16)
    __shared__ unsigned sortedE[CAPH];         // 8 KB pre-shifted edges (rel<<26 | src<<8)
    __shared__ unsigned short attl[1056];      // [65+][16] bf16 att (cols 8-15 & row 64 zero)
    __shared__ int doffsL[65];
    __shared__ int nextD;
    char* zt = (char*)ztV;

    int t = threadIdx.x;
    int bucket = blockIdx.x >> 1, half = blockIdx.x & 1;
    int w = t >> 6, lane = t & 63, lr = lane & 15, lg = lane >> 4;
    int l15 = lane & 15;
    int nb0 = bucket * 128 + half * 64;

    for (int i = t; i < 1040; i += 512) attl[i] = attBg[i];
    int rawIdx = bucket * 129 + half * 64;
    int rawBase = dstoffG[rawIdx];
    int cnt = min(dstoffG[rawIdx + 64] - rawBase, CAPH);
    if (t < 65) doffsL[t] = min(dstoffG[rawIdx + t] - rawBase, CAPH);
    if (t == 0) nextD = 0;
    int sG0 = bucketoff[bucket] + rawBase;
    for (int j = t; j < cnt; j += 512) {
        unsigned p = sortedG[sG0 + j];
        sortedE[j] = (((p >> 17) & 63u) << 26) | ((p & 0x1FFFFu) << 8);
    }
    __syncthreads();

    const char* xl = xswb + (l15 << 4);  // lane's 16B slice base within a row

    for (int r = 0; r < 4; ++r) {
        int rEnd = r * 16 + 16;

        // ---- accumulate: steal one dst; two nt-half passes with acc[4] live ----
        for (;;) {
            int my = 0x7FFFFFFF;
            if (lane == 0) my = atomicAdd(&nextD, 1);
            my = __shfl(my, 0, 64);
            if (my >= rEnd) break;
            int d = my;
            int eBeg = doffsL[d], eEnd = doffsL[d + 1];
            int cnt_d = eEnd - eBeg;
            int n = nb0 + d;
            unsigned xv = (n < N) ? x32[(size_t)n * 64 + lane] : 0u;  // prefetch x-append

            float inv = (cnt_d > 0) ? 1.f / (float)cnt_d : 0.f;
            int zr = d & 15, sw = zr & 7;
            char* zrow = zt + zr * ZROW;
            int last = eEnd - 1;

#pragma unroll 1
            for (int hp = 0; hp < 2; ++hp) {
                f32x4 acc[4];
#pragma unroll
                for (int q = 0; q < 4; ++q) acc[q] = (f32x4){0.f, 0.f, 0.f, 0.f};

                for (int c0 = eBeg; c0 < eEnd; c0 += 32) {
                    int kb = c0 + (lg << 3);
                    bf16x8 aF;
                    uint2 lo[8];
#pragma unroll
                    for (int j = 0; j < 8; ++j) {
                        int e = kb + j;
                        unsigned ew = sortedE[min(e, last)];
                        int arow = (e < eEnd) ? (int)(ew >> 26) : 64;
                        aF[j] = (short)attl[arow * 16 + l15];
                        lo[j] = *(const uint2*)(xl + (ew & 0x03FFFF00u) + hp * 8);
                    }
#pragma unroll
                    for (int q = 0; q < 4; ++q) {
                        unsigned sel = (q & 1) ? 0x03020706u : 0x01000504u;
                        int h = q >> 1;
                        unsigned bw[4];
                        bw[0] = __builtin_amdgcn_perm(((const unsigned*)&lo[0])[h],
                                                      ((const unsigned*)&lo[1])[h], sel);
                        bw[1] = __builtin_amdgcn_perm(((const unsigned*)&lo[2])[h],
                                                      ((const unsigned*)&lo[3])[h], sel);
                        bw[2] = __builtin_amdgcn_perm(((const unsigned*)&lo[4])[h],
                                                      ((const unsigned*)&lo[5])[h], sel);
                        bw[3] = __builtin_amdgcn_perm(((const unsigned*)&lo[6])[h],
                                                      ((const unsigned*)&lo[7])[h], sel);
                        acc[q] = __builtin_amdgcn_mfma_f32_16x16x32_bf16(
                            aF, *(const bf16x8*)&bw[0], acc[q], 0, 0, 0);
                    }
                }
                // flush this half's 4 nt rows
                if (lane < 32) {
                    int b0 = (lane >> 4) << 2;  // 0 or 4
#pragma unroll
                    for (int q = 0; q < 4; ++q) {
                        int chn = (hp * 4 + q) * 16 + l15;
                        uint2 v;
                        v.x = pack2bf(acc[q][0] * inv, acc[q][1] * inv);
                        v.y = pack2bf(acc[q][2] * inv, acc[q][3] * inv);
                        *(uint2*)(zrow + ((chn ^ sw) << 4) + (b0 << 1)) = v;
                    }
                }
            }
            *(unsigned*)(zrow + (((128 + (lane >> 2)) ^ sw) << 4) + ((lane & 3) << 2)) = xv;
        }
        __syncthreads();  // Z' tile ready

        // ---- big MFMA: D[oc][dst] over K=1152; 1 oc-tile per wave ----
        f32x4 accM = {0.f, 0.f, 0.f, 0.f};
        int ocr = w * 16 + lr;
        int swm = lr & 7;
#pragma unroll 6
        for (int kk = 0; kk < KST; ++kk) {
            bf16x8 a = *(const bf16x8*)(zt + lr * ZROW + ((((kk << 2) + lg) ^ swm) << 4));
            bf16x8 b0 = *(const bf16x8*)(basisP + ((((size_t)kk * 128 + ocr) * 4 + lg) << 3));
            accM = __builtin_amdgcn_mfma_f32_16x16x32_bf16(b0, a, accM, 0, 0, 0);
        }

        int n = nb0 + r * 16 + lr;
        if (n < N) {
            int oc0 = w * 16 + lg * 4;
            f32x4 bias = *(const f32x4*)(rb + oc0);
            *(f32x4*)(out + (size_t)n * NCH + oc0) = accM + bias;
        }
        if (t == 0) nextD = rEnd;  // reclaim overshoot for the next round
        __syncthreads();           // zt reads done before next round overwrites
    }
}

extern "C" void kernel_launch(void* const* d_in, const int* in_sizes, int n_in,
                              void* d_out, int out_size, void* d_ws, size_t ws_size,
                              hipStream_t stream) {
    const float* x = (const float*)d_in[0];
    const int* trip = (const int*)d_in[1];
    const float* basis = (const float*)d_in[3];
    const float* att = (const float*)d_in[4];
    const float* rw = (const float*)d_in[5];
    const float* rb = (const float*)d_in[6];
    float* out = (float*)d_out;

    int N = in_sizes[0] / NCH;        // 100000 (packing assumes N <= 131072)
    int E = in_sizes[1] / 3;
    int NB = (N + 127) >> 7;          // 782 buckets (<= NBP)
    int GB = (E + ESB - 1) / ESB;     // 391 blocks (<= 1024 for k_scanB)

    char* ws = (char*)d_ws;
    size_t off = 0;
    auto alloc = [&](size_t bts) { size_t o = off; off = (off + bts + 255) & ~(size_t)255; return o; };
    size_t oXbf    = alloc((size_t)N * NCH * 2);          // 25.6 MB (channel-swizzled)
    size_t oBasisP = alloc((size_t)128 * KTOT * 2);       // 288 KB
    size_t oAttB   = alloc(1056 * 2);
    size_t oCntB   = alloc((size_t)GB * NB * 4);          // ~1.2 MB
    size_t oBhist  = alloc((NBP + 1) * 4);
    size_t oBktoff = alloc((NBP + 1) * 4);
    size_t oPacked = alloc((size_t)E * 4);                // 6.4 MB
    size_t oSorted = alloc((size_t)E * 4);                // 6.4 MB
    size_t oDoff   = alloc((size_t)NB * 129 * 4);         // ~0.4 MB
    (void)off; (void)ws_size;                             // ~41 MB total

    unsigned short* x_sw = (unsigned short*)(ws + oXbf);
    unsigned short* basisP = (unsigned short*)(ws + oBasisP);
    unsigned short* attB = (unsigned short*)(ws + oAttB);
    int* cntB = (int*)(ws + oCntB);
    int* bhist = (int*)(ws + oBhist);
    int* bucketoff = (int*)(ws + oBktoff);
    unsigned* packed = (unsigned*)(ws + oPacked);
    unsigned* sortedG = (unsigned*)(ws + oSorted);
    int* dstoffG = (int*)(ws + oDoff);

    k_prep<<<(N * 16 + 255) / 256, 256, 0, stream>>>(x, x_sw, N);
    k_buildB<<<(128 * KTOT + 255) / 256, 256, 0, stream>>>(basis, att, rw, attB, basisP);
    k_count<<<GB, 256, 0, stream>>>(trip, E, NB, cntB);
    k_scanB<<<NB, 1024, 0, stream>>>(cntB, GB, NB, bhist);
    k_offsets<<<1, 1024, 0, stream>>>(bhist, NB, bucketoff);
    k_scatter<<<GB, 256, 0, stream>>>(trip, E, NB, cntB, bucketoff, packed);
    k_sortbkt<<<NB, 256, 0, stream>>>(packed, bucketoff, sortedG, dstoffG);
    k_fused<<<NB * 2, 512, 0, stream>>>((const unsigned*)x_sw, (const char*)x_sw, sortedG,
                                        bucketoff, dstoffG, attB, basisP, rb, out, N);
}

// Round 20
// 255.087 us; speedup vs baseline: 1.0614x; 1.0614x over previous
//
#include <hip/hip_runtime.h>

#define NCH 128
#define NREL 64
#define NBP 1024      // max 128-dst buckets
#define ESB 4096      // edges per count/scatter block
#define CAPF 3072     // max edges per bucket (mean ~2048)
#define CAPH 2048     // max edges per 64-dst half-bucket (mean ~1024)
#define KTOT 1152     // 1024 z-K (kappa = ch*8 + b) + 128 root-K
#define KST 36        // KTOT/32 k-steps
#define ZROW 2304     // bytes per z row (1152 bf16)

typedef __attribute__((ext_vector_type(8))) short bf16x8;
typedef __attribute__((ext_vector_type(4))) float f32x4;

__device__ __forceinline__ unsigned short f2bf(float f) {
    unsigned u = __float_as_uint(f);
    return (unsigned short)((u + 0x7fffu + ((u >> 16) & 1u)) >> 16);  // RNE
}
__device__ __forceinline__ unsigned pack2bf(float a, float b) {
    return (unsigned)f2bf(a) | ((unsigned)f2bf(b) << 16);
}

// ---------------- x (fp32) -> x_sw (bf16, channel-swizzled: i = l15*8+nt <-> c = nt*16+l15)
__global__ __launch_bounds__(256) void k_prep(const float* __restrict__ x,
                                              unsigned short* __restrict__ xsw,
                                              int N) {
    int idx = blockIdx.x * 256 + threadIdx.x;
    if (idx >= N * 16) return;
    int n = idx >> 4, l15 = idx & 15;
    const float* xr = x + (size_t)n * NCH + l15;
    bf16x8 p;
#pragma unroll
    for (int nt = 0; nt < 8; ++nt) p[nt] = (short)f2bf(xr[nt * 16]);
    *(bf16x8*)(xsw + (size_t)n * NCH + l15 * 8) = p;
}

// -------- basisP (MFMA-A layout): k<1024 -> basis[k&7][k>>3][oc]; root rows permuted -------
// -------- attB2[65][2][16] bf16: [rel][par][m] = (m>>3==par) ? att[rel][m&7] : 0 ----------
__global__ __launch_bounds__(256) void k_buildB(const float* __restrict__ basis,
                                                const float* __restrict__ att,
                                                const float* __restrict__ rw,
                                                unsigned short* __restrict__ attB2,
                                                unsigned short* __restrict__ basisP) {
    int idx = blockIdx.x * 256 + threadIdx.x;
    if (idx < 2080) {
        int rr = idx >> 5, p = (idx >> 4) & 1, m = idx & 15;
        attB2[idx] = (rr < NREL && (m >> 3) == p) ? f2bf(att[rr * 8 + (m & 7)])
                                                  : (unsigned short)0;
    }
    if (idx >= 128 * KTOT) return;
    int j = idx & 7, lg = (idx >> 3) & 3, oc = (idx >> 5) & 127, kk = idx >> 12;
    int k = kk * 32 + lg * 8 + j;
    float v;
    if (k < 1024) {
        int b = k & 7, ch = k >> 3;
        v = basis[(size_t)b * NCH * NCH + (size_t)ch * NCH + oc];
    } else {
        int kp = k - 1024;
        int ic = ((kp & 7) << 4) | (kp >> 3);  // x_sw channel permutation
        v = rw[(size_t)ic * NCH + oc];
    }
    basisP[idx] = f2bf(v);
}

// ---------------- per-block bucket histograms (no global atomics) ----------------
__global__ __launch_bounds__(256) void k_count(const int* __restrict__ trip, int E, int NB,
                                               int* __restrict__ cntB) {
    __shared__ int hb[NBP];
    int t = threadIdx.x;
    for (int i = t; i < NB; i += 256) hb[i] = 0;
    __syncthreads();
    int base = blockIdx.x * ESB;
#pragma unroll
    for (int i = 0; i < ESB / 256; ++i) {
        int e = base + i * 256 + t;
        if (e < E) atomicAdd(&hb[trip[3 * e + 2] >> 7], 1);
    }
    __syncthreads();
    for (int i = t; i < NB; i += 256) cntB[(size_t)blockIdx.x * NB + i] = hb[i];
}

// ---------------- column scan over blocks: cntB -> exclusive; bhist totals ----------------
__global__ __launch_bounds__(1024) void k_scanB(int* __restrict__ cntB, int GB, int NB,
                                                int* __restrict__ bhist) {
    __shared__ int sc[1024];
    int t = threadIdx.x, b = blockIdx.x;
    int v = (t < GB) ? cntB[(size_t)t * NB + b] : 0;
    sc[t] = v;
    __syncthreads();
    for (int off = 1; off < 1024; off <<= 1) {
        int a = (t >= off) ? sc[t - off] : 0;
        __syncthreads();
        sc[t] += a;
        __syncthreads();
    }
    if (t < GB) cntB[(size_t)t * NB + b] = sc[t] - v;
    if (t == GB - 1) bhist[b] = sc[t];
}

// ---------------- bucketoff from bhist ----------------
__global__ __launch_bounds__(1024) void k_offsets(const int* __restrict__ bhist, int NB,
                                                  int* __restrict__ bucketoff) {
    __shared__ int sc[1024];
    int t = threadIdx.x;
    int d = (t < NB) ? bhist[t] : 0;
    sc[t] = d;
    __syncthreads();
    for (int off = 1; off < 1024; off <<= 1) {
        int a = (t >= off) ? sc[t - off] : 0;
        __syncthreads();
        sc[t] += a;
        __syncthreads();
    }
    if (t < NB) bucketoff[t] = sc[t] - d;
    if (t == NB - 1) bucketoff[NB] = sc[t];
}

// ---------------- scatter: bucket-sorted packed edges (dst_low<<23 | rel<<17 | src) --------
__global__ __launch_bounds__(256) void k_scatter(const int* __restrict__ trip, int E, int NB,
                                                 const int* __restrict__ cntB,
                                                 const int* __restrict__ bucketoff,
                                                 unsigned* __restrict__ packed) {
    __shared__ int cb[NBP], lbase[NBP], delta[NBP];
    __shared__ int ssc[256];
    __shared__ unsigned lpk[ESB];
    __shared__ unsigned short lb[ESB];
    int t = threadIdx.x, blk = blockIdx.x;
    for (int i = t; i < NB; i += 256) cb[i] = 0;
    __syncthreads();
    int base = blk * ESB;
    int total = min(ESB, E - base);

    unsigned pk[ESB / 256];
    int rk[ESB / 256];
    unsigned short bk[ESB / 256];
#pragma unroll
    for (int i = 0; i < ESB / 256; ++i) {
        int e = base + i * 256 + t;
        pk[i] = 0; rk[i] = 0; bk[i] = 0;
        if (e < E) {
            int src = trip[3 * e], rel = trip[3 * e + 1], dst = trip[3 * e + 2];
            int bkt = dst >> 7;
            bk[i] = (unsigned short)bkt;
            pk[i] = ((unsigned)(dst & 127) << 23) | ((unsigned)rel << 17) | (unsigned)src;
            rk[i] = atomicAdd(&cb[bkt], 1);
        }
    }
    __syncthreads();
    int ch = (NB + 255) >> 8;
    int mysum = 0;
    for (int i = 0; i < ch; ++i) {
        int idx = t * ch + i;
        if (idx < NB) mysum += cb[idx];
    }
    ssc[t] = mysum;
    __syncthreads();
    for (int off = 1; off < 256; off <<= 1) {
        int a = (t >= off) ? ssc[t - off] : 0;
        __syncthreads();
        ssc[t] += a;
        __syncthreads();
    }
    int run = ssc[t] - mysum;
    for (int i = 0; i < ch; ++i) {
        int idx = t * ch + i;
        if (idx < NB) { lbase[idx] = run; run += cb[idx]; }
    }
    __syncthreads();
    for (int i = t; i < NB; i += 256)
        delta[i] = bucketoff[i] + cntB[(size_t)blk * NB + i] - lbase[i];
    __syncthreads();
#pragma unroll
    for (int i = 0; i < ESB / 256; ++i) {
        int e = base + i * 256 + t;
        if (e < E) {
            int j = lbase[bk[i]] + rk[i];
            lpk[j] = pk[i];
            lb[j] = bk[i];
        }
    }
    __syncthreads();
    for (int j = t; j < total; j += 256)
        packed[delta[lb[j]] + j] = lpk[j];
}

// ---------------- per-bucket dst_low counting sort -> sortedG + dstoffG ----------------
__global__ __launch_bounds__(256) void k_sortbkt(const unsigned* __restrict__ packed,
                                                 const int* __restrict__ bucketoff,
                                                 unsigned* __restrict__ sortedG,
                                                 int* __restrict__ dstoffG) {
    __shared__ int h[128], hs[128];
    int t = threadIdx.x, b = blockIdx.x;
    if (t < 128) h[t] = 0;
    __syncthreads();
    int s0 = bucketoff[b], s1 = bucketoff[b + 1];
    int cnt = min(s1 - s0, CAPF);

    unsigned pk[CAPF / 256];
    int rk[CAPF / 256];
#pragma unroll
    for (int i = 0; i < CAPF / 256; ++i) {
        int j = i * 256 + t;
        pk[i] = 0; rk[i] = 0;
        if (j < cnt) {
            unsigned p = packed[s0 + j];
            pk[i] = p;
            rk[i] = atomicAdd(&h[p >> 23], 1);
        }
    }
    __syncthreads();
    if (t < 128) hs[t] = h[t];
    __syncthreads();
    for (int off = 1; off < 128; off <<= 1) {
        int a = (t < 128 && t >= off) ? hs[t - off] : 0;
        __syncthreads();
        if (t < 128) hs[t] += a;
        __syncthreads();
    }
    if (t < 128) dstoffG[b * 129 + t] = hs[t] - h[t];  // exclusive, bucket-relative
    if (t == 0) dstoffG[b * 129 + 128] = cnt;
#pragma unroll
    for (int i = 0; i < CAPF / 256; ++i) {
        int j = i * 256 + t;
        if (j < cnt) {
            int d = pk[i] >> 23;
            sortedG[s0 + hs[d] - h[d] + rk[i]] = pk[i];
        }
    }
}

// ------- fused: dst-PAIR mini-MFMA (M rows 0-7 = dst0, 8-15 = dst1) + big MFMA -------------
__global__ __launch_bounds__(512, 4) void k_fused(const unsigned* __restrict__ x32,
                                                  const char* __restrict__ xswb,
                                                  const unsigned* __restrict__ sortedG,
                                                  const int* __restrict__ bucketoff,
                                                  const int* __restrict__ dstoffG,
                                                  const unsigned short* __restrict__ attBg,
                                                  const unsigned short* __restrict__ basisP,
                                                  const float* __restrict__ rb,
                                                  float* __restrict__ out, int N) {
    __shared__ bf16x8 ztV[16 * (ZROW / 16)];   // 36 KB swizzled Z' tile (16 dsts x 1152 bf16)
    __shared__ unsigned sortedE[CAPH];         // 8 KB edges: (rel<<26 | src<<8 | dst_parity)
    __shared__ unsigned short attl[2080];      // [65][2][16] bf16 att with parity masking
    __shared__ int doffsL[65];
    __shared__ int nextD;                      // pair counter
    char* zt = (char*)ztV;

    int t = threadIdx.x;
    int bucket = blockIdx.x >> 1, half = blockIdx.x & 1;
    int w = t >> 6, lane = t & 63, lr = lane & 15, lg = lane >> 4;
    int l15 = lane & 15;
    int nb0 = bucket * 128 + half * 64;

    for (int i = t; i < 2080; i += 512) attl[i] = attBg[i];
    int rawIdx = bucket * 129 + half * 64;
    int rawBase = dstoffG[rawIdx];
    int cnt = min(dstoffG[rawIdx + 64] - rawBase, CAPH);
    if (t < 65) doffsL[t] = min(dstoffG[rawIdx + t] - rawBase, CAPH);
    if (t == 0) nextD = 0;
    int sG0 = bucketoff[bucket] + rawBase;
    for (int j = t; j < cnt; j += 512) {
        unsigned p = sortedG[sG0 + j];
        sortedE[j] = (((p >> 17) & 63u) << 26) | ((p & 0x1FFFFu) << 8) | ((p >> 23) & 1u);
    }
    __syncthreads();

    const char* xl = xswb + (l15 << 4);  // lane's 16B slice base within a row

    for (int r = 0; r < 4; ++r) {
        int rEnd = r * 8 + 8;  // pairs

        // ---- accumulate: steal one dst PAIR; two nt-half passes with acc[4] live ----
        for (;;) {
            int my = 0x7FFFFFFF;
            if (lane == 0) my = atomicAdd(&nextD, 1);
            my = __shfl(my, 0, 64);
            if (my >= rEnd) break;
            int d0 = my * 2, d1 = d0 + 1;
            int eBeg = doffsL[d0], eMid = doffsL[d0 + 1], eEnd = doffsL[d0 + 2];
            int cnt0 = eMid - eBeg, cnt1 = eEnd - eMid;
            int n0 = nb0 + d0, n1 = nb0 + d1;
            unsigned xv0 = (n0 < N) ? x32[(size_t)n0 * 64 + lane] : 0u;
            unsigned xv1 = (n1 < N) ? x32[(size_t)n1 * 64 + lane] : 0u;

            float inv0 = (cnt0 > 0) ? 1.f / (float)cnt0 : 0.f;
            float inv1 = (cnt1 > 0) ? 1.f / (float)cnt1 : 0.f;
            int pr = lg >> 1;                         // which dst this lane's D rows hold
            float invM = pr ? inv1 : inv0;
            int dz = (pr ? d1 : d0) & 15;
            char* zrowM = zt + dz * ZROW;
            int swM = dz & 7;
            int b0 = (lg & 1) << 2;                   // 0 or 4 within the dst's 8 bases
            int last = eEnd - 1;

#pragma unroll 1
            for (int hp = 0; hp < 2; ++hp) {
                f32x4 acc[4];
#pragma unroll
                for (int q = 0; q < 4; ++q) acc[q] = (f32x4){0.f, 0.f, 0.f, 0.f};

                for (int c0 = eBeg; c0 < eEnd; c0 += 32) {
                    int kb = c0 + (lg << 3);
                    bf16x8 aF;
                    uint2 lo[8];
#pragma unroll
                    for (int j = 0; j < 8; ++j) {
                        int e = kb + j;
                        unsigned ew = sortedE[min(e, last)];
                        int arow = (e < eEnd) ? (int)(((ew >> 26) << 5) | ((ew & 1u) << 4))
                                              : 2048;
                        aF[j] = (short)attl[arow + l15];
                        lo[j] = *(const uint2*)(xl + (ew & 0x03FFFF00u) + hp * 8);
                    }
#pragma unroll
                    for (int q = 0; q < 4; ++q) {
                        unsigned sel = (q & 1) ? 0x03020706u : 0x01000504u;
                        int h = q >> 1;
                        unsigned bw[4];
                        bw[0] = __builtin_amdgcn_perm(((const unsigned*)&lo[0])[h],
                                                      ((const unsigned*)&lo[1])[h], sel);
                        bw[1] = __builtin_amdgcn_perm(((const unsigned*)&lo[2])[h],
                                                      ((const unsigned*)&lo[3])[h], sel);
                        bw[2] = __builtin_amdgcn_perm(((const unsigned*)&lo[4])[h],
                                                      ((const unsigned*)&lo[5])[h], sel);
                        bw[3] = __builtin_amdgcn_perm(((const unsigned*)&lo[6])[h],
                                                      ((const unsigned*)&lo[7])[h], sel);
                        acc[q] = __builtin_amdgcn_mfma_f32_16x16x32_bf16(
                            aF, *(const bf16x8*)&bw[0], acc[q], 0, 0, 0);
                    }
                }
                // flush this half's 4 nt rows (full wave: lg 0-1 -> dst0, lg 2-3 -> dst1)
#pragma unroll
                for (int q = 0; q < 4; ++q) {
                    int chn = (hp * 4 + q) * 16 + l15;
                    uint2 v;
                    v.x = pack2bf(acc[q][0] * invM, acc[q][1] * invM);
                    v.y = pack2bf(acc[q][2] * invM, acc[q][3] * invM);
                    *(uint2*)(zrowM + ((chn ^ swM) << 4) + (b0 << 1)) = v;
                }
            }
            // x-append rows for both dsts
            {
                int z0 = d0 & 15, z1 = d1 & 15;
                char* zr0 = zt + z0 * ZROW;
                char* zr1 = zt + z1 * ZROW;
                int u = 128 + (lane >> 2), sub = (lane & 3) << 2;
                *(unsigned*)(zr0 + (((u) ^ (z0 & 7)) << 4) + sub) = xv0;
                *(unsigned*)(zr1 + (((u) ^ (z1 & 7)) << 4) + sub) = xv1;
            }
        }
        __syncthreads();  // Z' tile ready

        // ---- big MFMA: D[oc][dst] over K=1152; 1 oc-tile per wave ----
        f32x4 accM = {0.f, 0.f, 0.f, 0.f};
        int ocr = w * 16 + lr;
        int swm = lr & 7;
#pragma unroll 6
        for (int kk = 0; kk < KST; ++kk) {
            bf16x8 a = *(const bf16x8*)(zt + lr * ZROW + ((((kk << 2) + lg) ^ swm) << 4));
            bf16x8 b0 = *(const bf16x8*)(basisP + ((((size_t)kk * 128 + ocr) * 4 + lg) << 3));
            accM = __builtin_amdgcn_mfma_f32_16x16x32_bf16(b0, a, accM, 0, 0, 0);
        }

        int n = nb0 + r * 16 + lr;
        if (n < N) {
            int oc0 = w * 16 + lg * 4;
            f32x4 bias = *(const f32x4*)(rb + oc0);
            *(f32x4*)(out + (size_t)n * NCH + oc0) = accM + bias;
        }
        if (t == 0) nextD = rEnd;  // reclaim overshoot for the next round
        __syncthreads();           // zt reads done before next round overwrites
    }
}

extern "C" void kernel_launch(void* const* d_in, const int* in_sizes, int n_in,
                              void* d_out, int out_size, void* d_ws, size_t ws_size,
                              hipStream_t stream) {
    const float* x = (const float*)d_in[0];
    const int* trip = (const int*)d_in[1];
    const float* basis = (const float*)d_in[3];
    const float* att = (const float*)d_in[4];
    const float* rw = (const float*)d_in[5];
    const float* rb = (const float*)d_in[6];
    float* out = (float*)d_out;

    int N = in_sizes[0] / NCH;        // 100000 (packing assumes N <= 131072)
    int E = in_sizes[1] / 3;
    int NB = (N + 127) >> 7;          // 782 buckets (<= NBP)
    int GB = (E + ESB - 1) / ESB;     // 391 blocks (<= 1024 for k_scanB)

    char* ws = (char*)d_ws;
    size_t off = 0;
    auto alloc = [&](size_t bts) { size_t o = off; off = (off + bts + 255) & ~(size_t)255; return o; };
    size_t oXbf    = alloc((size_t)N * NCH * 2);          // 25.6 MB (channel-swizzled)
    size_t oBasisP = alloc((size_t)128 * KTOT * 2);       // 288 KB
    size_t oAttB   = alloc(2080 * 2);
    size_t oCntB   = alloc((size_t)GB * NB * 4);          // ~1.2 MB
    size_t oBhist  = alloc((NBP + 1) * 4);
    size_t oBktoff = alloc((NBP + 1) * 4);
    size_t oPacked = alloc((size_t)E * 4);                // 6.4 MB
    size_t oSorted = alloc((size_t)E * 4);                // 6.4 MB
    size_t oDoff   = alloc((size_t)NB * 129 * 4);         // ~0.4 MB
    (void)off; (void)ws_size;                             // ~41 MB total

    unsigned short* x_sw = (unsigned short*)(ws + oXbf);
    unsigned short* basisP = (unsigned short*)(ws + oBasisP);
    unsigned short* attB = (unsigned short*)(ws + oAttB);
    int* cntB = (int*)(ws + oCntB);
    int* bhist = (int*)(ws + oBhist);
    int* bucketoff = (int*)(ws + oBktoff);
    unsigned* packed = (unsigned*)(ws + oPacked);
    unsigned* sortedG = (unsigned*)(ws + oSorted);
    int* dstoffG = (int*)(ws + oDoff);

    k_prep<<<(N * 16 + 255) / 256, 256, 0, stream>>>(x, x_sw, N);
    k_buildB<<<(128 * KTOT + 255) / 256, 256, 0, stream>>>(basis, att, rw, attB, basisP);
    k_count<<<GB, 256, 0, stream>>>(trip, E, NB, cntB);
    k_scanB<<<NB, 1024, 0, stream>>>(cntB, GB, NB, bhist);
    k_offsets<<<1, 1024, 0, stream>>>(bhist, NB, bucketoff);
    k_scatter<<<GB, 256, 0, stream>>>(trip, E, NB, cntB, bucketoff, packed);
    k_sortbkt<<<NB, 256, 0, stream>>>(packed, bucketoff, sortedG, dstoffG);
    k_fused<<<NB * 2, 512, 0, stream>>>((const unsigned*)x_sw, (const char*)x_sw, sortedG,
                                        bucketoff, dstoffG, attB, basisP, rb, out, N);
}

// Round 21
// 252.142 us; speedup vs baseline: 1.0738x; 1.0117x over previous
//
#include <hip/hip_runtime.h>

#define NCH 128
#define NREL 64
#define NBP 1024      // max 128-dst buckets
#define ESB 4096      // edges per count/scatter block
#define CAPF 3072     // max edges staged per bucket in k_sortbkt
#define CAPH 2304     // padded slot size per 64-dst half-bucket
#define KTOT 1152     // 1024 z-K (kappa = ch*8 + b) + 128 root-K
#define KST 36        // KTOT/32 k-steps
#define ZROW 2304     // bytes per z row (1152 bf16)

typedef __attribute__((ext_vector_type(8))) short bf16x8;
typedef __attribute__((ext_vector_type(4))) float f32x4;

__device__ __forceinline__ unsigned short f2bf(float f) {
    unsigned u = __float_as_uint(f);
    return (unsigned short)((u + 0x7fffu + ((u >> 16) & 1u)) >> 16);  // RNE
}
__device__ __forceinline__ unsigned pack2bf(float a, float b) {
    return (unsigned)f2bf(a) | ((unsigned)f2bf(b) << 16);
}

// ---------------- x (fp32) -> x_sw (bf16, channel-swizzled: i = l15*8+nt <-> c = nt*16+l15)
__global__ __launch_bounds__(256) void k_prep(const float* __restrict__ x,
                                              unsigned short* __restrict__ xsw,
                                              int N) {
    int idx = blockIdx.x * 256 + threadIdx.x;
    if (idx >= N * 16) return;
    int n = idx >> 4, l15 = idx & 15;
    const float* xr = x + (size_t)n * NCH + l15;
    bf16x8 p;
#pragma unroll
    for (int nt = 0; nt < 8; ++nt) p[nt] = (short)f2bf(xr[nt * 16]);
    *(bf16x8*)(xsw + (size_t)n * NCH + l15 * 8) = p;
}

// -------- basisP (MFMA-A layout): k<1024 -> basis[k&7][k>>3][oc]; root rows permuted -------
// -------- attB2[65][2][16] bf16: [rel][par][m] = (m>>3==par) ? att[rel][m&7] : 0 ----------
__global__ __launch_bounds__(256) void k_buildB(const float* __restrict__ basis,
                                                const float* __restrict__ att,
                                                const float* __restrict__ rw,
                                                unsigned short* __restrict__ attB2,
                                                unsigned short* __restrict__ basisP) {
    int idx = blockIdx.x * 256 + threadIdx.x;
    if (idx < 2080) {
        int rr = idx >> 5, p = (idx >> 4) & 1, m = idx & 15;
        attB2[idx] = (rr < NREL && (m >> 3) == p) ? f2bf(att[rr * 8 + (m & 7)])
                                                  : (unsigned short)0;
    }
    if (idx >= 128 * KTOT) return;
    int j = idx & 7, lg = (idx >> 3) & 3, oc = (idx >> 5) & 127, kk = idx >> 12;
    int k = kk * 32 + lg * 8 + j;
    float v;
    if (k < 1024) {
        int b = k & 7, ch = k >> 3;
        v = basis[(size_t)b * NCH * NCH + (size_t)ch * NCH + oc];
    } else {
        int kp = k - 1024;
        int ic = ((kp & 7) << 4) | (kp >> 3);  // x_sw channel permutation
        v = rw[(size_t)ic * NCH + oc];
    }
    basisP[idx] = f2bf(v);
}

// ---------------- per-block bucket histograms (no global atomics) ----------------
__global__ __launch_bounds__(256) void k_count(const int* __restrict__ trip, int E, int NB,
                                               int* __restrict__ cntB) {
    __shared__ int hb[NBP];
    int t = threadIdx.x;
    for (int i = t; i < NB; i += 256) hb[i] = 0;
    __syncthreads();
    int base = blockIdx.x * ESB;
#pragma unroll
    for (int i = 0; i < ESB / 256; ++i) {
        int e = base + i * 256 + t;
        if (e < E) atomicAdd(&hb[trip[3 * e + 2] >> 7], 1);
    }
    __syncthreads();
    for (int i = t; i < NB; i += 256) cntB[(size_t)blockIdx.x * NB + i] = hb[i];
}

// ---------------- column scan over blocks: cntB -> exclusive; bhist totals ----------------
__global__ __launch_bounds__(1024) void k_scanB(int* __restrict__ cntB, int GB, int NB,
                                                int* __restrict__ bhist) {
    __shared__ int sc[1024];
    int t = threadIdx.x, b = blockIdx.x;
    int v = (t < GB) ? cntB[(size_t)t * NB + b] : 0;
    sc[t] = v;
    __syncthreads();
    for (int off = 1; off < 1024; off <<= 1) {
        int a = (t >= off) ? sc[t - off] : 0;
        __syncthreads();
        sc[t] += a;
        __syncthreads();
    }
    if (t < GB) cntB[(size_t)t * NB + b] = sc[t] - v;
    if (t == GB - 1) bhist[b] = sc[t];
}

// ---------------- bucketoff from bhist ----------------
__global__ __launch_bounds__(1024) void k_offsets(const int* __restrict__ bhist, int NB,
                                                  int* __restrict__ bucketoff) {
    __shared__ int sc[1024];
    int t = threadIdx.x;
    int d = (t < NB) ? bhist[t] : 0;
    sc[t] = d;
    __syncthreads();
    for (int off = 1; off < 1024; off <<= 1) {
        int a = (t >= off) ? sc[t - off] : 0;
        __syncthreads();
        sc[t] += a;
        __syncthreads();
    }
    if (t < NB) bucketoff[t] = sc[t] - d;
    if (t == NB - 1) bucketoff[NB] = sc[t];
}

// ---------------- scatter: bucket-sorted packed edges (dst_low<<23 | rel<<17 | src) --------
__global__ __launch_bounds__(256) void k_scatter(const int* __restrict__ trip, int E, int NB,
                                                 const int* __restrict__ cntB,
                                                 const int* __restrict__ bucketoff,
                                                 unsigned* __restrict__ packed) {
    __shared__ int cb[NBP], lbase[NBP], delta[NBP];
    __shared__ int ssc[256];
    __shared__ unsigned lpk[ESB];
    __shared__ unsigned short lb[ESB];
    int t = threadIdx.x, blk = blockIdx.x;
    for (int i = t; i < NB; i += 256) cb[i] = 0;
    __syncthreads();
    int base = blk * ESB;
    int total = min(ESB, E - base);

    unsigned pk[ESB / 256];
    int rk[ESB / 256];
    unsigned short bk[ESB / 256];
#pragma unroll
    for (int i = 0; i < ESB / 256; ++i) {
        int e = base + i * 256 + t;
        pk[i] = 0; rk[i] = 0; bk[i] = 0;
        if (e < E) {
            int src = trip[3 * e], rel = trip[3 * e + 1], dst = trip[3 * e + 2];
            int bkt = dst >> 7;
            bk[i] = (unsigned short)bkt;
            pk[i] = ((unsigned)(dst & 127) << 23) | ((unsigned)rel << 17) | (unsigned)src;
            rk[i] = atomicAdd(&cb[bkt], 1);
        }
    }
    __syncthreads();
    int ch = (NB + 255) >> 8;
    int mysum = 0;
    for (int i = 0; i < ch; ++i) {
        int idx = t * ch + i;
        if (idx < NB) mysum += cb[idx];
    }
    ssc[t] = mysum;
    __syncthreads();
    for (int off = 1; off < 256; off <<= 1) {
        int a = (t >= off) ? ssc[t - off] : 0;
        __syncthreads();
        ssc[t] += a;
        __syncthreads();
    }
    int run = ssc[t] - mysum;
    for (int i = 0; i < ch; ++i) {
        int idx = t * ch + i;
        if (idx < NB) { lbase[idx] = run; run += cb[idx]; }
    }
    __syncthreads();
    for (int i = t; i < NB; i += 256)
        delta[i] = bucketoff[i] + cntB[(size_t)blk * NB + i] - lbase[i];
    __syncthreads();
#pragma unroll
    for (int i = 0; i < ESB / 256; ++i) {
        int e = base + i * 256 + t;
        if (e < E) {
            int j = lbase[bk[i]] + rk[i];
            lpk[j] = pk[i];
            lb[j] = bk[i];
        }
    }
    __syncthreads();
    for (int j = t; j < total; j += 256)
        packed[delta[lb[j]] + j] = lpk[j];
}

// ------- per-bucket sort into PADDED per-pair slots; sentinels fill the gaps ---------------
// sortedG layout: bucket b -> slot [b*2*CAPH, (b+1)*2*CAPH); half h at +h*CAPH.
__global__ __launch_bounds__(256) void k_sortbkt(const unsigned* __restrict__ packed,
                                                 const int* __restrict__ bucketoff,
                                                 unsigned* __restrict__ sortedG,
                                                 int* __restrict__ pairoffG,
                                                 int* __restrict__ dstcntG) {
    __shared__ int h[128];
    __shared__ int ppo[2][33];
    int t = threadIdx.x, b = blockIdx.x;
    if (t < 128) h[t] = 0;
    __syncthreads();
    int s0 = bucketoff[b], s1 = bucketoff[b + 1];
    int cnt = min(s1 - s0, CAPF);

    unsigned pk[CAPF / 256];
    int rk[CAPF / 256];
#pragma unroll
    for (int i = 0; i < CAPF / 256; ++i) {
        int j = i * 256 + t;
        pk[i] = 0; rk[i] = 0;
        if (j < cnt) {
            unsigned p = packed[s0 + j];
            pk[i] = p;
            rk[i] = atomicAdd(&h[p >> 23], 1);
        }
    }
    __syncthreads();
    if (t < 2) {  // padded pair offsets per half (serial over 32 pairs; tiny)
        int base2 = 0;
        for (int pl = 0; pl < 32; ++pl) {
            ppo[t][pl] = base2;
            int pc = h[t * 64 + 2 * pl] + h[t * 64 + 2 * pl + 1];
            int pad = ((pc + 31) >> 5) << 5;
            base2 = min(base2 + pad, CAPH);
        }
        ppo[t][32] = base2;
    }
    // sentinel pre-fill of the whole slot
    for (int j = t; j < 2 * CAPH; j += 256)
        sortedG[(size_t)b * 2 * CAPH + j] = 0x80000000u;
    __syncthreads();
    if (t < 128) dstcntG[b * 128 + t] = h[t];
    if (t < 33) pairoffG[(b * 2 + 0) * 33 + t] = ppo[0][t];
    else if (t < 66) pairoffG[(b * 2 + 1) * 33 + (t - 33)] = ppo[1][t - 33];
#pragma unroll
    for (int i = 0; i < CAPF / 256; ++i) {
        int j = i * 256 + t;
        if (j < cnt) {
            unsigned p = pk[i];
            int d = p >> 23;
            int half = d >> 6, pl = (d & 63) >> 1;
            int off = ppo[half][pl] + ((d & 1) ? h[d - 1] : 0) + rk[i];
            if (off < ppo[half][pl + 1])
                sortedG[(size_t)b * 2 * CAPH + half * CAPH + off] = p;
        }
    }
}

// ------- fused: dst-PAIR mini-MFMA, branch-free padded chunks + big MFMA -------------------
__global__ __launch_bounds__(512, 4) void k_fused(const unsigned* __restrict__ x32,
                                                  const char* __restrict__ xswb,
                                                  const unsigned* __restrict__ sortedG,
                                                  const int* __restrict__ pairoffG,
                                                  const int* __restrict__ dstcntG,
                                                  const unsigned short* __restrict__ attBg,
                                                  const unsigned short* __restrict__ basisP,
                                                  const float* __restrict__ rb,
                                                  float* __restrict__ out, int N) {
    __shared__ bf16x8 ztV[16 * (ZROW / 16)];   // 36 KB swizzled Z' tile (16 dsts x 1152 bf16)
    __shared__ unsigned sortedE[CAPH];         // 9 KB edges: arow<<20 | src (padded, aligned)
    __shared__ unsigned short attl[2080];      // [65][2][16] bf16 att with parity masking
    __shared__ int pairoffL[33];
    __shared__ float invL[64];
    __shared__ int nextD;                      // pair counter
    char* zt = (char*)ztV;

    int t = threadIdx.x;
    int bucket = blockIdx.x >> 1, half = blockIdx.x & 1;
    int w = t >> 6, lane = t & 63, lr = lane & 15, lg = lane >> 4;
    int l15 = lane & 15;
    int nb0 = bucket * 128 + half * 64;

    for (int i = t; i < 2080; i += 512) attl[i] = attBg[i];
    if (t < 33) pairoffL[t] = pairoffG[(bucket * 2 + half) * 33 + t];
    if (t >= 64 && t < 128) {
        int c = dstcntG[bucket * 128 + half * 64 + (t - 64)];
        invL[t - 64] = c ? 1.f / (float)c : 0.f;
    }
    if (t == 0) nextD = 0;
    int cntPad = pairoffG[(bucket * 2 + half) * 33 + 32];  // uniform scalar read
    size_t slotBase = (size_t)(bucket * 2 + half) * CAPH;
    for (int j = t; j < cntPad; j += 512) {
        unsigned p = sortedG[slotBase + j];
        unsigned word;
        if (p & 0x80000000u) word = (2048u << 20);
        else word = (((p >> 17) & 63u) << 25) | (((p >> 23) & 1u) << 24) | (p & 0x1FFFFu);
        sortedE[j] = word;
    }
    __syncthreads();

    const char* xl = xswb + (l15 << 4);  // lane's 16B slice base within a row

    for (int r = 0; r < 4; ++r) {
        int rEnd = r * 8 + 8;  // pairs

        // ---- accumulate: steal one dst PAIR; two nt-half passes, branch-free chunks ----
        for (;;) {
            int my = 0x7FFFFFFF;
            if (lane == 0) my = atomicAdd(&nextD, 1);
            my = __shfl(my, 0, 64);
            if (my >= rEnd) break;
            int d0 = my * 2, d1 = d0 + 1;
            int eBeg = pairoffL[my], eEnd = pairoffL[my + 1];
            int n0 = nb0 + d0, n1 = nb0 + d1;
            unsigned xv0 = (n0 < N) ? x32[(size_t)n0 * 64 + lane] : 0u;
            unsigned xv1 = (n1 < N) ? x32[(size_t)n1 * 64 + lane] : 0u;

            int pr = lg >> 1;                         // which dst this lane's D rows hold
            float invM = pr ? invL[d1] : invL[d0];
            int dz = (pr ? d1 : d0) & 15;
            char* zrowM = zt + dz * ZROW;
            int swM = dz & 7;
            int b0 = (lg & 1) << 2;                   // 0 or 4 within the dst's 8 bases

#pragma unroll 1
            for (int hp = 0; hp < 2; ++hp) {
                const char* xh = xl + hp * 8;
                f32x4 acc[4];
#pragma unroll
                for (int q = 0; q < 4; ++q) acc[q] = (f32x4){0.f, 0.f, 0.f, 0.f};

                for (int c0 = eBeg; c0 < eEnd; c0 += 32) {
                    int kb = c0 + (lg << 3);
                    bf16x8 aF;
                    uint2 lo[8];
#pragma unroll
                    for (int j = 0; j < 8; ++j) {
                        unsigned ew = sortedE[kb + j];
                        aF[j] = (short)attl[(ew >> 20) + l15];
                        lo[j] = *(const uint2*)(xh + ((ew & 0x1FFFFu) << 8));
                    }
#pragma unroll
                    for (int q = 0; q < 4; ++q) {
                        unsigned sel = (q & 1) ? 0x03020706u : 0x01000504u;
                        int h = q >> 1;
                        unsigned bw[4];
                        bw[0] = __builtin_amdgcn_perm(((const unsigned*)&lo[0])[h],
                                                      ((const unsigned*)&lo[1])[h], sel);
                        bw[1] = __builtin_amdgcn_perm(((const unsigned*)&lo[2])[h],
                                                      ((const unsigned*)&lo[3])[h], sel);
                        bw[2] = __builtin_amdgcn_perm(((const unsigned*)&lo[4])[h],
                                                      ((const unsigned*)&lo[5])[h], sel);
                        bw[3] = __builtin_amdgcn_perm(((const unsigned*)&lo[6])[h],
                                                      ((const unsigned*)&lo[7])[h], sel);
                        acc[q] = __builtin_amdgcn_mfma_f32_16x16x32_bf16(
                            aF, *(const bf16x8*)&bw[0], acc[q], 0, 0, 0);
                    }
                }
                // flush this half's 4 nt rows (full wave: lg 0-1 -> dst0, lg 2-3 -> dst1)
#pragma unroll
                for (int q = 0; q < 4; ++q) {
                    int chn = (hp * 4 + q) * 16 + l15;
                    uint2 v;
                    v.x = pack2bf(acc[q][0] * invM, acc[q][1] * invM);
                    v.y = pack2bf(acc[q][2] * invM, acc[q][3] * invM);
                    *(uint2*)(zrowM + ((chn ^ swM) << 4) + (b0 << 1)) = v;
                }
            }
            // x-append rows for both dsts
            {
                int z0 = d0 & 15, z1 = d1 & 15;
                char* zr0 = zt + z0 * ZROW;
                char* zr1 = zt + z1 * ZROW;
                int u = 128 + (lane >> 2), sub = (lane & 3) << 2;
                *(unsigned*)(zr0 + (((u) ^ (z0 & 7)) << 4) + sub) = xv0;
                *(unsigned*)(zr1 + (((u) ^ (z1 & 7)) << 4) + sub) = xv1;
            }
        }
        __syncthreads();  // Z' tile ready

        // ---- big MFMA: D[oc][dst] over K=1152; 1 oc-tile per wave ----
        f32x4 accM = {0.f, 0.f, 0.f, 0.f};
        int ocr = w * 16 + lr;
        int swm = lr & 7;
#pragma unroll 6
        for (int kk = 0; kk < KST; ++kk) {
            bf16x8 a = *(const bf16x8*)(zt + lr * ZROW + ((((kk << 2) + lg) ^ swm) << 4));
            bf16x8 b0 = *(const bf16x8*)(basisP + ((((size_t)kk * 128 + ocr) * 4 + lg) << 3));
            accM = __builtin_amdgcn_mfma_f32_16x16x32_bf16(b0, a, accM, 0, 0, 0);
        }

        int n = nb0 + r * 16 + lr;
        if (n < N) {
            int oc0 = w * 16 + lg * 4;
            f32x4 bias = *(const f32x4*)(rb + oc0);
            *(f32x4*)(out + (size_t)n * NCH + oc0) = accM + bias;
        }
        if (t == 0) nextD = rEnd;  // reclaim overshoot for the next round
        __syncthreads();           // zt reads done before next round overwrites
    }
}

extern "C" void kernel_launch(void* const* d_in, const int* in_sizes, int n_in,
                              void* d_out, int out_size, void* d_ws, size_t ws_size,
                              hipStream_t stream) {
    const float* x = (const float*)d_in[0];
    const int* trip = (const int*)d_in[1];
    const float* basis = (const float*)d_in[3];
    const float* att = (const float*)d_in[4];
    const float* rw = (const float*)d_in[5];
    const float* rb = (const float*)d_in[6];
    float* out = (float*)d_out;

    int N = in_sizes[0] / NCH;        // 100000 (packing assumes N <= 131072)
    int E = in_sizes[1] / 3;
    int NB = (N + 127) >> 7;          // 782 buckets (<= NBP)
    int GB = (E + ESB - 1) / ESB;     // 391 blocks (<= 1024 for k_scanB)

    char* ws = (char*)d_ws;
    size_t off = 0;
    auto alloc = [&](size_t bts) { size_t o = off; off = (off + bts + 255) & ~(size_t)255; return o; };
    size_t oXbf    = alloc((size_t)N * NCH * 2);          // 25.6 MB (channel-swizzled)
    size_t oBasisP = alloc((size_t)128 * KTOT * 2);       // 288 KB
    size_t oAttB   = alloc(2080 * 2);
    size_t oCntB   = alloc((size_t)GB * NB * 4);          // ~1.2 MB
    size_t oBhist  = alloc((NBP + 1) * 4);
    size_t oBktoff = alloc((NBP + 1) * 4);
    size_t oPacked = alloc((size_t)E * 4);                // 6.4 MB
    size_t oSorted = alloc((size_t)NB * 2 * CAPH * 4);    // 14.4 MB padded slots
    size_t oPairoff = alloc((size_t)NB * 2 * 33 * 4);     // ~206 KB
    size_t oDstcnt = alloc((size_t)NB * 128 * 4);         // ~400 KB
    (void)off; (void)ws_size;                             // ~49 MB total

    unsigned short* x_sw = (unsigned short*)(ws + oXbf);
    unsigned short* basisP = (unsigned short*)(ws + oBasisP);
    unsigned short* attB = (unsigned short*)(ws + oAttB);
    int* cntB = (int*)(ws + oCntB);
    int* bhist = (int*)(ws + oBhist);
    int* bucketoff = (int*)(ws + oBktoff);
    unsigned* packed = (unsigned*)(ws + oPacked);
    unsigned* sortedG = (unsigned*)(ws + oSorted);
    int* pairoffG = (int*)(ws + oPairoff);
    int* dstcntG = (int*)(ws + oDstcnt);

    k_prep<<<(N * 16 + 255) / 256, 256, 0, stream>>>(x, x_sw, N);
    k_buildB<<<(128 * KTOT + 255) / 256, 256, 0, stream>>>(basis, att, rw, attB, basisP);
    k_count<<<GB, 256, 0, stream>>>(trip, E, NB, cntB);
    k_scanB<<<NB, 1024, 0, stream>>>(cntB, GB, NB, bhist);
    k_offsets<<<1, 1024, 0, stream>>>(bhist, NB, bucketoff);
    k_scatter<<<GB, 256, 0, stream>>>(trip, E, NB, cntB, bucketoff, packed);
    k_sortbkt<<<NB, 256, 0, stream>>>(packed, bucketoff, sortedG, pairoffG, dstcntG);
    k_fused<<<NB * 2, 512, 0, stream>>>((const unsigned*)x_sw, (const char*)x_sw, sortedG,
                                        pairoffG, dstcntG, attB, basisP, rb, out, N);
}